// Round 1
// baseline (211.331 us; speedup 1.0000x reference)
//
#include <hip/hip_runtime.h>

#define BATCH    8192
#define CTX      32
#define ROUTES   24
#define EDIM     128
#define NSLICE   24
#define WAVES_PER_BLOCK 4

__global__ __launch_bounds__(256) void tale_main(
    const int* __restrict__ context,            // (B, C)
    const int* __restrict__ route,              // (B, R)
    const int* __restrict__ lr,                 // (B, R)
    const int* __restrict__ slice_idx,          // (B,)
    const float* __restrict__ input_embed,      // (NUM_LOC, E)
    const float* __restrict__ inner_node_embed, // (NUM_INNER+1, E)
    const float* __restrict__ slice_node_embed, // (NSLICE, E)
    float* __restrict__ ws_sum)
{
    const int lane = threadIdx.x & 63;
    const int waveInBlock = threadIdx.x >> 6;
    const int b = blockIdx.x * WAVES_PER_BLOCK + waveInBlock;

    __shared__ float blockSums[WAVES_PER_BLOCK];

    // ---- load per-row indices into lanes, broadcast later via shuffle ----
    int cidx = 0, ridx = 0, lridx = 0;
    if (lane < CTX) cidx = context[b * CTX + lane];
    if (lane < ROUTES) {
        ridx  = route[b * ROUTES + lane];
        lridx = lr[b * ROUTES + lane];
    }
    const int si = slice_idx[b];

    // ---- context embedding sum: lane owns dims (2*lane, 2*lane+1) ----
    float2 ctx = make_float2(0.f, 0.f);
    #pragma unroll
    for (int c = 0; c < CTX; ++c) {
        const int idx = __shfl(cidx, c);
        const float2 v = *reinterpret_cast<const float2*>(
            &input_embed[(size_t)idx * EDIM + 2 * lane]);
        ctx.x += v.x;
        ctx.y += v.y;
    }

    // ---- slice softmax (online, no logit array) ----
    float m = -3.0e38f;   // running max
    float d = 0.f;        // running rescaled denom
    float sel = 0.f;      // logit at slice_idx
    #pragma unroll
    for (int s = 0; s < NSLICE; ++s) {
        const float2 w = *reinterpret_cast<const float2*>(
            &slice_node_embed[s * EDIM + 2 * lane]);
        float p = w.x * ctx.x + w.y * ctx.y;
        #pragma unroll
        for (int off = 32; off > 0; off >>= 1) p += __shfl_xor(p, off);
        // p is now the full logit, identical in all lanes
        const float mNew = fmaxf(m, p);
        d = d * __expf(m - mNew) + __expf(p - mNew);
        m = mNew;
        if (s == si) sel = p;
    }
    const float slice_pre = __expf(sel - m) / d;

    // ---- route product ----
    float prod = 1.f;
    #pragma unroll
    for (int r = 0; r < ROUTES; ++r) {
        const int idx = __shfl(ridx, r);
        const int l   = __shfl(lridx, r);
        const float2 v = *reinterpret_cast<const float2*>(
            &inner_node_embed[(size_t)idx * EDIM + 2 * lane]);
        float p = v.x * ctx.x + v.y * ctx.y;
        #pragma unroll
        for (int off = 32; off > 0; off >>= 1) p += __shfl_xor(p, off);
        const float sg = 1.f / (1.f + __expf(-p));
        float h = l ? sg : (1.f - sg);
        if (idx == 0) h = 1.f;   // padded route position -> factor 1
        prod *= h;
    }

    const float pr = slice_pre * prod;

    if (lane == 0) blockSums[waveInBlock] = pr;
    __syncthreads();
    if (threadIdx.x == 0) {
        float s = 0.f;
        #pragma unroll
        for (int w = 0; w < WAVES_PER_BLOCK; ++w) s += blockSums[w];
        atomicAdd(ws_sum, s);
    }
}

__global__ void tale_finalize(const float* __restrict__ ws_sum,
                              float* __restrict__ out)
{
    out[0] = 1.0f - ws_sum[0] * (1.0f / (float)BATCH);
}

extern "C" void kernel_launch(void* const* d_in, const int* in_sizes, int n_in,
                              void* d_out, int out_size, void* d_ws, size_t ws_size,
                              hipStream_t stream)
{
    const int*   context          = (const int*)  d_in[0];
    const int*   route            = (const int*)  d_in[1];
    const int*   lr               = (const int*)  d_in[2];
    const int*   slice_idx        = (const int*)  d_in[3];
    const float* input_embed      = (const float*)d_in[4];
    const float* inner_node_embed = (const float*)d_in[5];
    const float* slice_node_embed = (const float*)d_in[6];
    float* out = (float*)d_out;
    float* ws  = (float*)d_ws;

    // zero the accumulator (ws is poisoned 0xAA before every launch)
    hipMemsetAsync(ws, 0, sizeof(float), stream);

    tale_main<<<BATCH / WAVES_PER_BLOCK, 64 * WAVES_PER_BLOCK, 0, stream>>>(
        context, route, lr, slice_idx,
        input_embed, inner_node_embed, slice_node_embed, ws);

    tale_finalize<<<1, 1, 0, stream>>>(ws, out);
}

// Round 2
// 207.101 us; speedup vs baseline: 1.0204x; 1.0204x over previous
//
#include <hip/hip_runtime.h>

#define BATCH    8192
#define CTX      32
#define ROUTES   24
#define EDIM     128
#define NSLICE   24
#define WPB      4
#define NBLOCKS  (BATCH / WPB)

// One wave per batch row. Within a wave: lanes are split into two 32-lane
// halves; each half owns one full E=128 row per vector load (32 lanes x
// float4 = 512B coalesced). All dot-product reductions are 5-step butterflies
// within a half, so each tree reduces TWO dots at once (half 0 -> even dot,
// half 1 -> odd dot).
__global__ __launch_bounds__(256, 8) void tale_fused(
    const int* __restrict__ context,            // (B, C)
    const int* __restrict__ route,              // (B, R)
    const int* __restrict__ lr,                 // (B, R)
    const int* __restrict__ slice_idx,          // (B,)
    const float* __restrict__ input_embed,      // (NUM_LOC, E)
    const float* __restrict__ inner_node_embed, // (NUM_INNER+1, E)
    const float* __restrict__ slice_node_embed, // (NSLICE, E)
    float* __restrict__ out)
{
    const int tid  = threadIdx.x;
    const int lane = tid & 63;
    const int half = lane >> 5;        // 0 = lower half, 1 = upper half
    const int sub  = lane & 31;        // lane within half; owns dims 4*sub..4*sub+3
    const int w    = tid >> 6;
    const int b    = blockIdx.x * WPB + w;

    __shared__ float bs[WPB];

    // ---- per-row indices (held one-per-lane, broadcast via shuffle) ----
    int cidx = 0, ridx = 0, lridx = 0;
    if (lane < CTX) cidx = context[b * CTX + lane];
    if (lane < ROUTES) {
        ridx  = route[b * ROUTES + lane];
        lridx = lr[b * ROUTES + lane];
    }
    const int si = slice_idx[b];

    // ---- context embedding sum ----
    // iteration i: lower half loads context entry i, upper half entry i+16
    float4 acc = make_float4(0.f, 0.f, 0.f, 0.f);
    #pragma unroll
    for (int i = 0; i < 16; ++i) {
        const int idx = __shfl(cidx, i + (half << 4));
        const float4 v = *reinterpret_cast<const float4*>(
            input_embed + (size_t)idx * EDIM + (sub << 2));
        acc.x += v.x; acc.y += v.y; acc.z += v.z; acc.w += v.w;
    }
    // combine the two halves' partial sums -> full ctx chunk in every lane
    acc.x += __shfl_xor(acc.x, 32);
    acc.y += __shfl_xor(acc.y, 32);
    acc.z += __shfl_xor(acc.z, 32);
    acc.w += __shfl_xor(acc.w, 32);
    // lane now holds ctx[4*sub .. 4*sub+3]

    // ---- route products: 12 iterations, dots (2i, 2i+1) in the two halves ----
    float prodv = 1.f;
    #pragma unroll
    for (int i = 0; i < 12; ++i) {
        const int d   = 2 * i + half;
        const int idx = __shfl(ridx, d);
        const int l   = __shfl(lridx, d);
        const float4 v = *reinterpret_cast<const float4*>(
            inner_node_embed + (size_t)idx * EDIM + (sub << 2));
        float p = v.x * acc.x + v.y * acc.y + v.z * acc.z + v.w * acc.w;
        p += __shfl_xor(p, 16);
        p += __shfl_xor(p, 8);
        p += __shfl_xor(p, 4);
        p += __shfl_xor(p, 2);
        p += __shfl_xor(p, 1);          // p = full dot, uniform within half
        const float sg = 1.f / (1.f + __expf(-p));
        float h = l ? sg : (1.f - sg);
        if (idx == 0) h = 1.f;          // padded route position
        prodv *= h;
    }
    prodv *= __shfl_xor(prodv, 32);     // even-half product * odd-half product

    // ---- slice softmax: two independent online chains (even/odd slices) ----
    float m = -3.0e38f, den = 0.f, selv = 0.f;
    #pragma unroll
    for (int i = 0; i < 12; ++i) {
        const int s = 2 * i + half;
        const float4 v = *reinterpret_cast<const float4*>(
            slice_node_embed + s * EDIM + (sub << 2));
        float p = v.x * acc.x + v.y * acc.y + v.z * acc.z + v.w * acc.w;
        p += __shfl_xor(p, 16);
        p += __shfl_xor(p, 8);
        p += __shfl_xor(p, 4);
        p += __shfl_xor(p, 2);
        p += __shfl_xor(p, 1);
        const float mN = fmaxf(m, p);
        den = den * __expf(m - mN) + __expf(p - mN);
        m = mN;
        if (s == si) selv = p;
    }
    // merge the two online-softmax chains across halves
    const float m_o   = __shfl_xor(m, 32);
    const float den_o = __shfl_xor(den, 32);
    const float M     = fmaxf(m, m_o);
    const float dtot  = den * __expf(m - M) + den_o * __expf(m_o - M);
    const float sel   = __shfl(selv, (si & 1) << 5);  // logit of target slice
    const float slice_pre = __expf(sel - M) / dtot;

    const float pr = slice_pre * prodv;

    if (lane == 0) bs[w] = pr;
    __syncthreads();
    if (tid == 0) {
        const float s = bs[0] + bs[1] + bs[2] + bs[3];
        // out = sum over blocks of (1/NBLOCKS - blockSum/B) = 1 - mean
        atomicAdd(out, 1.0f / NBLOCKS - s * (1.0f / BATCH));
    }
}

extern "C" void kernel_launch(void* const* d_in, const int* in_sizes, int n_in,
                              void* d_out, int out_size, void* d_ws, size_t ws_size,
                              hipStream_t stream)
{
    const int*   context          = (const int*)  d_in[0];
    const int*   route            = (const int*)  d_in[1];
    const int*   lr               = (const int*)  d_in[2];
    const int*   slice_idx        = (const int*)  d_in[3];
    const float* input_embed      = (const float*)d_in[4];
    const float* inner_node_embed = (const float*)d_in[5];
    const float* slice_node_embed = (const float*)d_in[6];
    float* out = (float*)d_out;

    // d_out is poisoned 0xAA before every launch; zero it, then blocks
    // atomic-accumulate (1/NBLOCKS - blockSum/B) so the final value is 1-mean.
    hipMemsetAsync(out, 0, sizeof(float), stream);

    tale_fused<<<NBLOCKS, 64 * WPB, 0, stream>>>(
        context, route, lr, slice_idx,
        input_embed, inner_node_embed, slice_node_embed, out);
}